// Round 1
// baseline (9681.911 us; speedup 1.0000x reference)
//
#include <hip/hip_runtime.h>
#include <math.h>

#define WW 32
#define FF 16
#define HH 64

__device__ __forceinline__ float fsig(float v) { return 1.0f / (1.0f + __expf(-v)); }
__device__ __forceinline__ float ftanh(float v) { return 1.0f - 2.0f / (1.0f + __expf(2.0f * v)); }

// ---------------- LSTM: one thread per node, 64-thread blocks ----------------
__global__ __launch_bounds__(64) void lstm_kernel(
    const float* __restrict__ x,      // [N,32,16]
    const float* __restrict__ W_ih,   // [256,16]
    const float* __restrict__ W_hh,   // [256,64]
    const float* __restrict__ b_ih,   // [256]
    const float* __restrict__ b_hh,   // [256]
    float* __restrict__ h_out,        // [N,64]
    int nN)
{
    // [dim][tid] layout: wave accesses are lane-contiguous -> conflict-free.
    __shared__ float h_lds[2][HH][64];
    __shared__ float c_lds[HH][64];
    const int tid = threadIdx.x;
    const int n = blockIdx.x * 64 + tid;
    const bool active = (n < nN);

    #pragma unroll
    for (int k = 0; k < HH; k++) { h_lds[0][k][tid] = 0.0f; c_lds[k][tid] = 0.0f; }

    const float* xp = x + (size_t)(active ? n : 0) * (WW * FF);

    for (int t = 0; t < WW; t++) {
        float xt[FF];
        {
            const float4* xv = reinterpret_cast<const float4*>(xp + t * FF);
            float4 q0 = xv[0], q1 = xv[1], q2 = xv[2], q3 = xv[3];
            xt[0]=q0.x; xt[1]=q0.y; xt[2]=q0.z; xt[3]=q0.w;
            xt[4]=q1.x; xt[5]=q1.y; xt[6]=q1.z; xt[7]=q1.w;
            xt[8]=q2.x; xt[9]=q2.y; xt[10]=q2.z; xt[11]=q2.w;
            xt[12]=q3.x; xt[13]=q3.y; xt[14]=q3.z; xt[15]=q3.w;
        }
        const int rb = t & 1;
        const int wb = rb ^ 1;
        for (int j = 0; j < HH; j++) {
            // combined biases (wave-uniform scalar loads)
            float ai = b_ih[j]        + b_hh[j];
            float af = b_ih[HH + j]   + b_hh[HH + j];
            float ag = b_ih[2*HH + j] + b_hh[2*HH + j];
            float ao = b_ih[3*HH + j] + b_hh[3*HH + j];
            const float* wi = W_ih + j * FF;
            #pragma unroll
            for (int k = 0; k < FF; k++) {
                const float xk = xt[k];
                ai = fmaf(xk, wi[k],            ai);
                af = fmaf(xk, wi[HH*FF   + k],  af);
                ag = fmaf(xk, wi[2*HH*FF + k],  ag);
                ao = fmaf(xk, wi[3*HH*FF + k],  ao);
            }
            const float* wh = W_hh + j * HH;
            #pragma unroll
            for (int k = 0; k < HH; k++) {
                const float hk = h_lds[rb][k][tid];
                ai = fmaf(hk, wh[k],            ai);
                af = fmaf(hk, wh[HH*HH   + k],  af);
                ag = fmaf(hk, wh[2*HH*HH + k],  ag);
                ao = fmaf(hk, wh[3*HH*HH + k],  ao);
            }
            const float ig = fsig(ai);
            const float fg = fsig(af);
            const float gg = ftanh(ag);
            const float og = fsig(ao);
            const float c = fg * c_lds[j][tid] + ig * gg;
            c_lds[j][tid] = c;
            h_lds[wb][j][tid] = og * ftanh(c);
        }
    }
    if (active) {
        #pragma unroll
        for (int k = 0; k < HH; k++) h_out[(size_t)n * HH + k] = h_lds[0][k][tid];  // WW even -> final in buf 0
    }
}

// ---------------- degree / dis ----------------
__global__ void zero_kernel(float* __restrict__ p, int n) {
    int i = blockIdx.x * 256 + threadIdx.x;
    if (i < n) p[i] = 0.0f;
}

__global__ void deg_kernel(const int* __restrict__ dst, float* __restrict__ deg, int nE, int nN) {
    int e = blockIdx.x * 256 + threadIdx.x;
    if (e < nE) {
        int d = dst[e];
        if ((unsigned)d < (unsigned)nN) atomicAdd(&deg[d], 1.0f);
    }
}

__global__ void dis_kernel(float* __restrict__ deg_dis, int nN) {
    int i = blockIdx.x * 256 + threadIdx.x;
    if (i < nN) deg_dis[i] = rsqrtf(deg_dis[i] + 1.0f);
}

// ---------------- xw = act(in) @ W : wave per node ----------------
template<bool RELU_BIAS>
__global__ void xw_kernel(const float* __restrict__ A, const float* __restrict__ W,
                          const float* __restrict__ bias, float* __restrict__ out, int nN)
{
    const int wave = threadIdx.x >> 6;
    const int lane = threadIdx.x & 63;
    const int n = blockIdx.x * 4 + wave;
    if (n >= nN) return;
    const float* arow = A + (size_t)n * HH;
    float acc = 0.0f;
    #pragma unroll
    for (int k = 0; k < HH; k++) {
        float a = arow[k];
        if (RELU_BIAS) a = fmaxf(a + bias[k], 0.0f);
        acc = fmaf(a, W[k * HH + lane], acc);
    }
    out[(size_t)n * HH + lane] = acc;
}

// ---------------- agg init (self-loop term) ----------------
__global__ void agg_init_kernel(const float* __restrict__ xw, const float* __restrict__ dis,
                                float* __restrict__ agg, int nN)
{
    size_t i = (size_t)blockIdx.x * 256 + threadIdx.x;
    if (i >= (size_t)nN * HH) return;
    int n = (int)(i >> 6);
    float d = dis[n];
    agg[i] = xw[i] * d * d;
}

// ---------------- edge scatter: one wave per edge ----------------
__global__ void scatter_kernel(const float* __restrict__ xw, const float* __restrict__ dis,
                               const int* __restrict__ src, const int* __restrict__ dst,
                               float* __restrict__ agg, int nE, int nN)
{
    const int e = blockIdx.x * 4 + (threadIdx.x >> 6);
    const int lane = threadIdx.x & 63;
    if (e >= nE) return;
    int s = src[e], d = dst[e];
    if ((unsigned)s >= (unsigned)nN || (unsigned)d >= (unsigned)nN) return;
    const float coef = dis[s] * dis[d];
    const float v = xw[(size_t)s * HH + lane] * coef;
    atomicAdd(&agg[(size_t)d * HH + lane], v);
}

// ---------------- head: out = relu(agg+b2) @ W_lin + b_lin ----------------
__global__ void head_kernel(const float* __restrict__ agg, const float* __restrict__ b2,
                            const float* __restrict__ W_lin, const float* __restrict__ b_lin,
                            float* __restrict__ out, int nN)
{
    const int wave = threadIdx.x >> 6;
    const int lane = threadIdx.x & 63;
    const int n = blockIdx.x * 4 + wave;
    if (n >= nN) return;
    float v = fmaxf(agg[(size_t)n * HH + lane] + b2[lane], 0.0f) * W_lin[lane];
    #pragma unroll
    for (int off = 32; off > 0; off >>= 1) v += __shfl_down(v, off);
    if (lane == 0) out[n] = v + b_lin[0];
}

extern "C" void kernel_launch(void* const* d_in, const int* in_sizes, int n_in,
                              void* d_out, int out_size, void* d_ws, size_t ws_size,
                              hipStream_t stream)
{
    const float* x     = (const float*)d_in[0];
    const int*   edge  = (const int*)d_in[1];
    const float* W_ih  = (const float*)d_in[2];
    const float* W_hh  = (const float*)d_in[3];
    const float* b_ih  = (const float*)d_in[4];
    const float* b_hh  = (const float*)d_in[5];
    const float* W1    = (const float*)d_in[6];
    const float* b1    = (const float*)d_in[7];
    const float* W2    = (const float*)d_in[8];
    const float* b2    = (const float*)d_in[9];
    const float* W_lin = (const float*)d_in[10];
    const float* b_lin = (const float*)d_in[11];
    float* out = (float*)d_out;

    const int nN = in_sizes[0] / (WW * FF);   // 100000
    const int nE = in_sizes[1] / 2;           // 1600000
    const int* src = edge;
    const int* dst = edge + nE;

    float* ws = (float*)d_ws;
    const size_t npad = ((size_t)nN + 255) & ~(size_t)255;
    float* dis = ws;                       // [N]
    float* A   = ws + npad;                // [N,64]
    float* B   = A + (size_t)nN * HH;      // [N,64]
    float* C   = B + (size_t)nN * HH;      // [N,64]

    const size_t NH = (size_t)nN * HH;

    // degree -> dis
    zero_kernel<<<(nN + 255) / 256, 256, 0, stream>>>(dis, nN);
    deg_kernel<<<(nE + 255) / 256, 256, 0, stream>>>(dst, dis, nE, nN);
    dis_kernel<<<(nN + 255) / 256, 256, 0, stream>>>(dis, nN);

    // LSTM -> A = h_last
    lstm_kernel<<<(nN + 63) / 64, 64, 0, stream>>>(x, W_ih, W_hh, b_ih, b_hh, A, nN);

    // GCN layer 1: B = A @ W1 ; C = agg
    xw_kernel<false><<<(nN + 3) / 4, 256, 0, stream>>>(A, W1, nullptr, B, nN);
    agg_init_kernel<<<(int)((NH + 255) / 256), 256, 0, stream>>>(B, dis, C, nN);
    scatter_kernel<<<(nE + 3) / 4, 256, 0, stream>>>(B, dis, src, dst, C, nE, nN);

    // GCN layer 2: A = relu(C + b1) @ W2 ; B = agg
    xw_kernel<true><<<(nN + 3) / 4, 256, 0, stream>>>(C, W2, b1, A, nN);
    agg_init_kernel<<<(int)((NH + 255) / 256), 256, 0, stream>>>(A, dis, B, nN);
    scatter_kernel<<<(nE + 3) / 4, 256, 0, stream>>>(A, dis, src, dst, B, nE, nN);

    // head
    head_kernel<<<(nN + 3) / 4, 256, 0, stream>>>(B, b2, W_lin, b_lin, out, nN);
}

// Round 2
// 7596.021 us; speedup vs baseline: 1.2746x; 1.2746x over previous
//
#include <hip/hip_runtime.h>
#include <math.h>

#define WW 32
#define FF 16
#define HH 64

__device__ __forceinline__ float fsig(float v) { return 1.0f / (1.0f + __expf(-v)); }
__device__ __forceinline__ float ftanh(float v) { return 1.0f - 2.0f / (1.0f + __expf(2.0f * v)); }

__device__ __forceinline__ void load16(float* r, const float* p) {
    const float4* v = reinterpret_cast<const float4*>(p);
    float4 q0 = v[0], q1 = v[1], q2 = v[2], q3 = v[3];
    r[0]=q0.x; r[1]=q0.y; r[2]=q0.z; r[3]=q0.w;
    r[4]=q1.x; r[5]=q1.y; r[6]=q1.z; r[7]=q1.w;
    r[8]=q2.x; r[9]=q2.y; r[10]=q2.z; r[11]=q2.w;
    r[12]=q3.x; r[13]=q3.y; r[14]=q3.z; r[15]=q3.w;
}

// ---------------- LSTM: one thread per node, h kept in REGISTERS ----------------
// LDS only stages the dynamic-index writes (h_new[j], c[j]); 32KB/block -> 5 blocks/CU.
// Inner loop: pure v_fma_f32 with SGPR weight operands (wave-uniform j).
__global__ __launch_bounds__(64) void lstm_kernel(
    const float* __restrict__ x,      // [N,32,16]
    const float* __restrict__ W_ih,   // [256,16]
    const float* __restrict__ W_hh,   // [256,64]
    const float* __restrict__ b_ih,   // [256]
    const float* __restrict__ b_hh,   // [256]
    float* __restrict__ h_out,        // [N,64]
    int nN)
{
    __shared__ float hstage[HH][64];  // [dim][tid]: lanes contiguous -> conflict-free
    __shared__ float cbuf[HH][64];
    const int tid = threadIdx.x;
    const int n = blockIdx.x * 64 + tid;
    const bool active = (n < nN);

    float h[HH];
    #pragma unroll
    for (int k = 0; k < HH; k++) { h[k] = 0.0f; cbuf[k][tid] = 0.0f; }

    const float* xp = x + (size_t)(active ? n : 0) * (WW * FF);

    float xt[FF];
    load16(xt, xp);  // t = 0

    for (int t = 0; t < WW; t++) {
        // prefetch next timestep's x (clamped to stay in-bounds on last iter)
        float xn[FF];
        const int tn = (t + 1 < WW) ? (t + 1) : (WW - 1);
        load16(xn, xp + tn * FF);

        for (int j = 0; j < HH; j++) {
            float ai = b_ih[j]        + b_hh[j];
            float af = b_ih[HH + j]   + b_hh[HH + j];
            float ag = b_ih[2*HH + j] + b_hh[2*HH + j];
            float ao = b_ih[3*HH + j] + b_hh[3*HH + j];
            const float* wi = W_ih + j * FF;
            #pragma unroll
            for (int k = 0; k < FF; k++) {
                const float xk = xt[k];
                ai = fmaf(xk, wi[k],            ai);
                af = fmaf(xk, wi[HH*FF   + k],  af);
                ag = fmaf(xk, wi[2*HH*FF + k],  ag);
                ao = fmaf(xk, wi[3*HH*FF + k],  ao);
            }
            const float* wh = W_hh + j * HH;
            #pragma unroll
            for (int k = 0; k < HH; k++) {
                const float hk = h[k];          // register, static index
                ai = fmaf(hk, wh[k],            ai);
                af = fmaf(hk, wh[HH*HH   + k],  af);
                ag = fmaf(hk, wh[2*HH*HH + k],  ag);
                ao = fmaf(hk, wh[3*HH*HH + k],  ao);
            }
            const float ig = fsig(ai);
            const float fg = fsig(af);
            const float gg = ftanh(ag);
            const float og = fsig(ao);
            const float c = fg * cbuf[j][tid] + ig * gg;
            cbuf[j][tid] = c;
            hstage[j][tid] = og * ftanh(c);
        }
        // copy staged h_new back into registers (static indices)
        #pragma unroll
        for (int k = 0; k < HH; k++) h[k] = hstage[k][tid];
        #pragma unroll
        for (int k = 0; k < FF; k++) xt[k] = xn[k];
    }
    if (active) {
        #pragma unroll
        for (int k = 0; k < HH; k += 4) {
            float4 q = make_float4(h[k], h[k+1], h[k+2], h[k+3]);
            *reinterpret_cast<float4*>(h_out + (size_t)n * HH + k) = q;
        }
    }
}

// ---------------- degree / dis ----------------
__global__ void zero_kernel(float* __restrict__ p, int n) {
    int i = blockIdx.x * 256 + threadIdx.x;
    if (i < n) p[i] = 0.0f;
}

__global__ void deg_kernel(const int* __restrict__ dst, float* __restrict__ deg, int nE, int nN) {
    int e = blockIdx.x * 256 + threadIdx.x;
    if (e < nE) {
        int d = dst[e];
        if ((unsigned)d < (unsigned)nN) atomicAdd(&deg[d], 1.0f);
    }
}

__global__ void dis_kernel(float* __restrict__ deg_dis, int nN) {
    int i = blockIdx.x * 256 + threadIdx.x;
    if (i < nN) deg_dis[i] = rsqrtf(deg_dis[i] + 1.0f);
}

// ---------------- xw = act(in) @ W, fused with agg self-loop init ----------------
template<bool RELU_BIAS>
__global__ void xw_kernel(const float* __restrict__ A, const float* __restrict__ W,
                          const float* __restrict__ bias, const float* __restrict__ dis,
                          float* __restrict__ xw_out, float* __restrict__ agg_out, int nN)
{
    const int wave = threadIdx.x >> 6;
    const int lane = threadIdx.x & 63;
    const int n = blockIdx.x * 4 + wave;
    if (n >= nN) return;
    const float* arow = A + (size_t)n * HH;
    float acc = 0.0f;
    #pragma unroll
    for (int k = 0; k < HH; k++) {
        float a = arow[k];
        if (RELU_BIAS) a = fmaxf(a + bias[k], 0.0f);
        acc = fmaf(a, W[k * HH + lane], acc);
    }
    const float d = dis[n];
    xw_out[(size_t)n * HH + lane] = acc;
    agg_out[(size_t)n * HH + lane] = acc * d * d;   // self-loop term
}

// ---------------- edge scatter: one wave per edge ----------------
__global__ void scatter_kernel(const float* __restrict__ xw, const float* __restrict__ dis,
                               const int* __restrict__ src, const int* __restrict__ dst,
                               float* __restrict__ agg, int nE, int nN)
{
    const int e = blockIdx.x * 4 + (threadIdx.x >> 6);
    const int lane = threadIdx.x & 63;
    if (e >= nE) return;
    int s = src[e], d = dst[e];
    if ((unsigned)s >= (unsigned)nN || (unsigned)d >= (unsigned)nN) return;
    const float coef = dis[s] * dis[d];
    const float v = xw[(size_t)s * HH + lane] * coef;
    atomicAdd(&agg[(size_t)d * HH + lane], v);
}

// ---------------- head: out = relu(agg+b2) @ W_lin + b_lin ----------------
__global__ void head_kernel(const float* __restrict__ agg, const float* __restrict__ b2,
                            const float* __restrict__ W_lin, const float* __restrict__ b_lin,
                            float* __restrict__ out, int nN)
{
    const int wave = threadIdx.x >> 6;
    const int lane = threadIdx.x & 63;
    const int n = blockIdx.x * 4 + wave;
    if (n >= nN) return;
    float v = fmaxf(agg[(size_t)n * HH + lane] + b2[lane], 0.0f) * W_lin[lane];
    #pragma unroll
    for (int off = 32; off > 0; off >>= 1) v += __shfl_down(v, off);
    if (lane == 0) out[n] = v + b_lin[0];
}

extern "C" void kernel_launch(void* const* d_in, const int* in_sizes, int n_in,
                              void* d_out, int out_size, void* d_ws, size_t ws_size,
                              hipStream_t stream)
{
    const float* x     = (const float*)d_in[0];
    const int*   edge  = (const int*)d_in[1];
    const float* W_ih  = (const float*)d_in[2];
    const float* W_hh  = (const float*)d_in[3];
    const float* b_ih  = (const float*)d_in[4];
    const float* b_hh  = (const float*)d_in[5];
    const float* W1    = (const float*)d_in[6];
    const float* b1    = (const float*)d_in[7];
    const float* W2    = (const float*)d_in[8];
    const float* b2    = (const float*)d_in[9];
    const float* W_lin = (const float*)d_in[10];
    const float* b_lin = (const float*)d_in[11];
    float* out = (float*)d_out;

    const int nN = in_sizes[0] / (WW * FF);   // 100000
    const int nE = in_sizes[1] / 2;           // 1600000
    const int* src = edge;
    const int* dst = edge + nE;

    float* ws = (float*)d_ws;
    const size_t npad = ((size_t)nN + 255) & ~(size_t)255;
    float* dis = ws;                       // [N]
    float* A   = ws + npad;                // [N,64]
    float* B   = A + (size_t)nN * HH;      // [N,64]
    float* C   = B + (size_t)nN * HH;      // [N,64]

    // degree -> dis
    zero_kernel<<<(nN + 255) / 256, 256, 0, stream>>>(dis, nN);
    deg_kernel<<<(nE + 255) / 256, 256, 0, stream>>>(dst, dis, nE, nN);
    dis_kernel<<<(nN + 255) / 256, 256, 0, stream>>>(dis, nN);

    // LSTM -> A = h_last
    lstm_kernel<<<(nN + 63) / 64, 64, 0, stream>>>(x, W_ih, W_hh, b_ih, b_hh, A, nN);

    // GCN layer 1: B = A @ W1 ; C = agg (self-loop init fused)
    xw_kernel<false><<<(nN + 3) / 4, 256, 0, stream>>>(A, W1, nullptr, dis, B, C, nN);
    scatter_kernel<<<(nE + 3) / 4, 256, 0, stream>>>(B, dis, src, dst, C, nE, nN);

    // GCN layer 2: A = relu(C + b1) @ W2 ; B = agg (self-loop init fused)
    xw_kernel<true><<<(nN + 3) / 4, 256, 0, stream>>>(C, W2, b1, dis, A, B, nN);
    scatter_kernel<<<(nE + 3) / 4, 256, 0, stream>>>(A, dis, src, dst, B, nE, nN);

    // head
    head_kernel<<<(nN + 3) / 4, 256, 0, stream>>>(B, b2, W_lin, b_lin, out, nN);
}

// Round 3
// 4265.759 us; speedup vs baseline: 2.2697x; 1.7807x over previous
//
#include <hip/hip_runtime.h>
#include <math.h>

#define WW 32
#define FF 16
#define HH 64
#define JW 16   // j's per wave (64 j / 4 waves)

__device__ __forceinline__ float fsig(float v) { return 1.0f / (1.0f + __expf(-v)); }
__device__ __forceinline__ float ftanh(float v) { return 1.0f - 2.0f / (1.0f + __expf(2.0f * v)); }

__device__ __forceinline__ void load16(float* r, const float* p) {
    const float4* v = reinterpret_cast<const float4*>(p);
    float4 q0 = v[0], q1 = v[1], q2 = v[2], q3 = v[3];
    r[0]=q0.x; r[1]=q0.y; r[2]=q0.z; r[3]=q0.w;
    r[4]=q1.x; r[5]=q1.y; r[6]=q1.z; r[7]=q1.w;
    r[8]=q2.x; r[9]=q2.y; r[10]=q2.z; r[11]=q2.w;
    r[12]=q3.x; r[13]=q3.y; r[14]=q3.z; r[15]=q3.w;
}

// ---------------- LSTM: 4-wave cooperative block, 64 nodes/block ----------------
// lane = node (same 64 nodes for all 4 waves); wave w computes gate rows
// j in [16w, 16w+16). h lives in LDS [j][lane] (lane-contiguous, conflict-free),
// re-read into registers each timestep; c rows are owned by a single wave.
// Weight addresses are wave-uniform (j0 via readfirstlane) -> scalar s_loads.
__global__ __launch_bounds__(256) void lstm_kernel(
    const float* __restrict__ x,      // [N,32,16]
    const float* __restrict__ W_ih,   // [256,16]
    const float* __restrict__ W_hh,   // [256,64]
    const float* __restrict__ b_ih,   // [256]
    const float* __restrict__ b_hh,   // [256]
    float* __restrict__ h_out,        // [N,64]
    int nN)
{
    __shared__ float h_lds[HH][64];
    __shared__ float c_lds[HH][64];
    const int lane = threadIdx.x & 63;
    const int wv   = __builtin_amdgcn_readfirstlane(threadIdx.x >> 6);  // provably uniform
    const int j0   = wv * JW;
    const int n    = blockIdx.x * 64 + lane;
    const bool active = (n < nN);

    #pragma unroll
    for (int u = 0; u < JW; u++) { h_lds[j0 + u][lane] = 0.0f; c_lds[j0 + u][lane] = 0.0f; }
    __syncthreads();

    const float* xp = x + (size_t)(active ? n : 0) * (WW * FF);

    for (int t = 0; t < WW; t++) {
        float xt[FF];
        load16(xt, xp + t * FF);

        // snapshot previous h into registers (conflict-free: lanes contiguous)
        float h[HH];
        #pragma unroll
        for (int k = 0; k < HH; k++) h[k] = h_lds[k][lane];
        __syncthreads();   // all waves done reading old h before overwrite

        #pragma unroll 4
        for (int u = 0; u < JW; u++) {
            const int j = j0 + u;
            float ai = b_ih[j]        + b_hh[j];
            float af = b_ih[HH + j]   + b_hh[HH + j];
            float ag = b_ih[2*HH + j] + b_hh[2*HH + j];
            float ao = b_ih[3*HH + j] + b_hh[3*HH + j];
            const float* wi = W_ih + j * FF;
            #pragma unroll
            for (int k = 0; k < FF; k++) {
                const float xk = xt[k];
                ai = fmaf(xk, wi[k],            ai);
                af = fmaf(xk, wi[HH*FF   + k],  af);
                ag = fmaf(xk, wi[2*HH*FF + k],  ag);
                ao = fmaf(xk, wi[3*HH*FF + k],  ao);
            }
            const float* wh = W_hh + j * HH;
            #pragma unroll
            for (int k = 0; k < HH; k++) {
                const float hk = h[k];          // register, static index
                ai = fmaf(hk, wh[k],            ai);
                af = fmaf(hk, wh[HH*HH   + k],  af);
                ag = fmaf(hk, wh[2*HH*HH + k],  ag);
                ao = fmaf(hk, wh[3*HH*HH + k],  ao);
            }
            const float ig = fsig(ai);
            const float fg = fsig(af);
            const float gg = ftanh(ag);
            const float og = fsig(ao);
            const float c = fg * c_lds[j][lane] + ig * gg;
            c_lds[j][lane] = c;
            h_lds[j][lane] = og * ftanh(c);
        }
        __syncthreads();   // new h visible before next timestep's reads
    }

    if (active) {
        #pragma unroll
        for (int u = 0; u < JW; u++) h_out[(size_t)n * HH + j0 + u] = h_lds[j0 + u][lane];
    }
}

// ---------------- degree / dis ----------------
__global__ void zero_kernel(float* __restrict__ p, int n) {
    int i = blockIdx.x * 256 + threadIdx.x;
    if (i < n) p[i] = 0.0f;
}

__global__ void deg_kernel(const int* __restrict__ dst, float* __restrict__ deg, int nE, int nN) {
    int e = blockIdx.x * 256 + threadIdx.x;
    if (e < nE) {
        int d = dst[e];
        if ((unsigned)d < (unsigned)nN) atomicAdd(&deg[d], 1.0f);
    }
}

__global__ void dis_kernel(float* __restrict__ deg_dis, int nN) {
    int i = blockIdx.x * 256 + threadIdx.x;
    if (i < nN) deg_dis[i] = rsqrtf(deg_dis[i] + 1.0f);
}

// ---------------- xw = act(in) @ W, fused with agg self-loop init ----------------
template<bool RELU_BIAS>
__global__ void xw_kernel(const float* __restrict__ A, const float* __restrict__ W,
                          const float* __restrict__ bias, const float* __restrict__ dis,
                          float* __restrict__ xw_out, float* __restrict__ agg_out, int nN)
{
    const int wave = threadIdx.x >> 6;
    const int lane = threadIdx.x & 63;
    const int n = blockIdx.x * 4 + wave;
    if (n >= nN) return;
    const float* arow = A + (size_t)n * HH;
    float acc = 0.0f;
    #pragma unroll
    for (int k = 0; k < HH; k++) {
        float a = arow[k];
        if (RELU_BIAS) a = fmaxf(a + bias[k], 0.0f);
        acc = fmaf(a, W[k * HH + lane], acc);
    }
    const float d = dis[n];
    xw_out[(size_t)n * HH + lane] = acc;
    agg_out[(size_t)n * HH + lane] = acc * d * d;   // self-loop term
}

// ---------------- edge scatter: one wave per edge ----------------
__global__ void scatter_kernel(const float* __restrict__ xw, const float* __restrict__ dis,
                               const int* __restrict__ src, const int* __restrict__ dst,
                               float* __restrict__ agg, int nE, int nN)
{
    const int e = blockIdx.x * 4 + (threadIdx.x >> 6);
    const int lane = threadIdx.x & 63;
    if (e >= nE) return;
    int s = src[e], d = dst[e];
    if ((unsigned)s >= (unsigned)nN || (unsigned)d >= (unsigned)nN) return;
    const float coef = dis[s] * dis[d];
    const float v = xw[(size_t)s * HH + lane] * coef;
    atomicAdd(&agg[(size_t)d * HH + lane], v);
}

// ---------------- head: out = relu(agg+b2) @ W_lin + b_lin ----------------
__global__ void head_kernel(const float* __restrict__ agg, const float* __restrict__ b2,
                            const float* __restrict__ W_lin, const float* __restrict__ b_lin,
                            float* __restrict__ out, int nN)
{
    const int wave = threadIdx.x >> 6;
    const int lane = threadIdx.x & 63;
    const int n = blockIdx.x * 4 + wave;
    if (n >= nN) return;
    float v = fmaxf(agg[(size_t)n * HH + lane] + b2[lane], 0.0f) * W_lin[lane];
    #pragma unroll
    for (int off = 32; off > 0; off >>= 1) v += __shfl_down(v, off);
    if (lane == 0) out[n] = v + b_lin[0];
}

extern "C" void kernel_launch(void* const* d_in, const int* in_sizes, int n_in,
                              void* d_out, int out_size, void* d_ws, size_t ws_size,
                              hipStream_t stream)
{
    const float* x     = (const float*)d_in[0];
    const int*   edge  = (const int*)d_in[1];
    const float* W_ih  = (const float*)d_in[2];
    const float* W_hh  = (const float*)d_in[3];
    const float* b_ih  = (const float*)d_in[4];
    const float* b_hh  = (const float*)d_in[5];
    const float* W1    = (const float*)d_in[6];
    const float* b1    = (const float*)d_in[7];
    const float* W2    = (const float*)d_in[8];
    const float* b2    = (const float*)d_in[9];
    const float* W_lin = (const float*)d_in[10];
    const float* b_lin = (const float*)d_in[11];
    float* out = (float*)d_out;

    const int nN = in_sizes[0] / (WW * FF);   // 100000
    const int nE = in_sizes[1] / 2;           // 1600000
    const int* src = edge;
    const int* dst = edge + nE;

    float* ws = (float*)d_ws;
    const size_t npad = ((size_t)nN + 255) & ~(size_t)255;
    float* dis = ws;                       // [N]
    float* A   = ws + npad;                // [N,64]
    float* B   = A + (size_t)nN * HH;      // [N,64]
    float* C   = B + (size_t)nN * HH;      // [N,64]

    // degree -> dis
    zero_kernel<<<(nN + 255) / 256, 256, 0, stream>>>(dis, nN);
    deg_kernel<<<(nE + 255) / 256, 256, 0, stream>>>(dst, dis, nE, nN);
    dis_kernel<<<(nN + 255) / 256, 256, 0, stream>>>(dis, nN);

    // LSTM -> A = h_last
    lstm_kernel<<<(nN + 63) / 64, 256, 0, stream>>>(x, W_ih, W_hh, b_ih, b_hh, A, nN);

    // GCN layer 1: B = A @ W1 ; C = agg (self-loop init fused)
    xw_kernel<false><<<(nN + 3) / 4, 256, 0, stream>>>(A, W1, nullptr, dis, B, C, nN);
    scatter_kernel<<<(nE + 3) / 4, 256, 0, stream>>>(B, dis, src, dst, C, nE, nN);

    // GCN layer 2: A = relu(C + b1) @ W2 ; B = agg (self-loop init fused)
    xw_kernel<true><<<(nN + 3) / 4, 256, 0, stream>>>(C, W2, b1, dis, A, B, nN);
    scatter_kernel<<<(nE + 3) / 4, 256, 0, stream>>>(A, dis, src, dst, B, nE, nN);

    // head
    head_kernel<<<(nN + 3) / 4, 256, 0, stream>>>(B, b2, W_lin, b_lin, out, nN);
}

// Round 4
// 1795.388 us; speedup vs baseline: 5.3927x; 2.3760x over previous
//
#include <hip/hip_runtime.h>
#include <math.h>

#define WW 32
#define FF 16
#define HH 64

typedef __attribute__((ext_vector_type(8))) short bf16x8;
typedef __attribute__((ext_vector_type(4))) float f32x4;

__device__ __forceinline__ unsigned short bf16h(float f) {
    unsigned int u = __float_as_uint(f);
    unsigned int r = (u + 0x7FFFu + ((u >> 16) & 1u)) >> 16;
    return (unsigned short)r;
}
__device__ __forceinline__ float bf16f(unsigned short h) {
    return __uint_as_float(((unsigned int)h) << 16);
}
__device__ __forceinline__ float fsig(float v)  { return __fdividef(1.0f, 1.0f + __expf(-v)); }
__device__ __forceinline__ float ftanh(float v) { return 1.0f - __fdividef(2.0f, 1.0f + __expf(2.0f * v)); }

__device__ __forceinline__ void split_store4(short* dhi, short* dlo, float4 v) {
    short4 h, l;
    unsigned short t;
    t = bf16h(v.x); h.x = (short)t; l.x = (short)bf16h(v.x - bf16f(t));
    t = bf16h(v.y); h.y = (short)t; l.y = (short)bf16h(v.y - bf16f(t));
    t = bf16h(v.z); h.z = (short)t; l.z = (short)bf16h(v.z - bf16f(t));
    t = bf16h(v.w); h.w = (short)t; l.w = (short)bf16h(v.w - bf16f(t));
    *reinterpret_cast<short4*>(dhi) = h;
    *reinterpret_cast<short4*>(dlo) = l;
}

// ---------------- LSTM via MFMA (split-bf16 = fp32 accuracy) ----------------
// Block = 256 threads = 64 nodes. Wave w owns dim-tile w: gate col-tiles
// {w, w+4, w+8, w+12} (gates i,f,g,o for dims 16w..16w+15). gates = Z @ Wcat^T,
// Z = [x(16) | h(64) | pad(16)] as bf16 hi/lo planes in LDS (double-buffered).
// C-frag: row(node) = 4*(lane>>4)+reg, col = lane&15 (m89-verified) -> c-state
// stays in registers; i/f/g/o frags are position-aligned.
__global__ __launch_bounds__(256, 2) void lstm_mfma_kernel(
    const float* __restrict__ x,      // [N,32,16]
    const float* __restrict__ W_ih,   // [256,16]
    const float* __restrict__ W_hh,   // [256,64]
    const float* __restrict__ b_ih,   // [256]
    const float* __restrict__ b_hh,   // [256]
    float* __restrict__ h_out,        // [N,64]
    int nN)
{
    __shared__ short Z[2][2][64][104];  // [buf][hi=0/lo=1][node][dim] dims:0-15 x,16-79 h,80+ pad
    const int tid  = threadIdx.x;
    const int lane = tid & 63;
    const int wv   = tid >> 6;
    const int l15  = lane & 15;
    const int g    = lane >> 4;
    const int n0   = blockIdx.x * 64;

    // ---- W (B-operand) fragments + bias, once per block ----
    bf16x8 Bh[4][3], Bl[4][3];
    float bias[4];
    #pragma unroll
    for (int gate = 0; gate < 4; gate++) {
        const int j = 16 * wv + 64 * gate + l15;   // row of Wcat in [0,256)
        bias[gate] = b_ih[j] + b_hh[j];
        #pragma unroll
        for (int q = 0; q < 3; q++) {
            const int k0 = 32 * q + 8 * g;         // global k of elems 0..7
            float v[8];
            if (k0 < 16) {
                const float4* p = reinterpret_cast<const float4*>(W_ih + j * FF + k0);
                float4 a = p[0], b = p[1];
                v[0]=a.x; v[1]=a.y; v[2]=a.z; v[3]=a.w; v[4]=b.x; v[5]=b.y; v[6]=b.z; v[7]=b.w;
            } else if (k0 < 80) {
                const float4* p = reinterpret_cast<const float4*>(W_hh + j * HH + (k0 - 16));
                float4 a = p[0], b = p[1];
                v[0]=a.x; v[1]=a.y; v[2]=a.z; v[3]=a.w; v[4]=b.x; v[5]=b.y; v[6]=b.z; v[7]=b.w;
            } else {
                #pragma unroll
                for (int i = 0; i < 8; i++) v[i] = 0.0f;
            }
            bf16x8 hi, lo;
            #pragma unroll
            for (int i = 0; i < 8; i++) {
                unsigned short hb = bf16h(v[i]);
                hi[i] = (short)hb;
                lo[i] = (short)bf16h(v[i] - bf16f(hb));
            }
            Bh[gate][q] = hi; Bl[gate][q] = lo;
        }
    }

    // ---- prologue: zero pad cols (both bufs) + h-region (buf0), stage x_0 ----
    const int node_s = tid >> 2;
    const int qq     = tid & 3;
    {
        #pragma unroll
        for (int b = 0; b < 2; b++)
            #pragma unroll
            for (int s = 0; s < 2; s++)
                #pragma unroll
                for (int c = 0; c < 6; c++)
                    Z[b][s][node_s][80 + qq * 6 + c] = 0;
        #pragma unroll
        for (int s = 0; s < 2; s++)
            #pragma unroll
            for (int c = 0; c < 16; c++)
                Z[0][s][node_s][16 + qq * 16 + c] = 0;
        int gn = n0 + node_s; if (gn >= nN) gn = nN - 1;
        const float4 xf = *reinterpret_cast<const float4*>(x + (size_t)gn * (WW * FF) + qq * 4);
        split_store4(&Z[0][0][node_s][qq * 4], &Z[0][1][node_s][qq * 4], xf);
    }
    __syncthreads();

    f32x4 cst[4] = {{0.f,0.f,0.f,0.f},{0.f,0.f,0.f,0.f},{0.f,0.f,0.f,0.f},{0.f,0.f,0.f,0.f}};

    for (int t = 0; t < WW; t++) {
        short (*Zc)[64][104] = Z[t & 1];
        short (*Zn)[64][104] = Z[(t & 1) ^ 1];

        // prefetch x_{t+1} (global -> reg, written to Zn after compute)
        int gn = n0 + node_s; if (gn >= nN) gn = nN - 1;
        const int tn = (t + 1 < WW) ? (t + 1) : (WW - 1);
        const float4 xf = *reinterpret_cast<const float4*>(x + (size_t)gn * (WW * FF) + tn * FF + qq * 4);

        #pragma unroll
        for (int rt = 0; rt < 4; rt++) {
            const int m = 16 * rt + l15;   // A row = node in block
            bf16x8 Ah[3], Al[3];
            #pragma unroll
            for (int q = 0; q < 3; q++) {
                const int k0 = 32 * q + 8 * g;
                Ah[q] = *reinterpret_cast<const bf16x8*>(&Zc[0][m][k0]);
                Al[q] = *reinterpret_cast<const bf16x8*>(&Zc[1][m][k0]);
            }
            f32x4 acc[4];
            #pragma unroll
            for (int gate = 0; gate < 4; gate++) {
                f32x4 ini = {bias[gate], bias[gate], bias[gate], bias[gate]};
                acc[gate] = ini;
            }
            #pragma unroll
            for (int q = 0; q < 3; q++) {
                #pragma unroll
                for (int gate = 0; gate < 4; gate++) {
                    acc[gate] = __builtin_amdgcn_mfma_f32_16x16x32_bf16(Ah[q], Bh[gate][q], acc[gate], 0, 0, 0);
                    acc[gate] = __builtin_amdgcn_mfma_f32_16x16x32_bf16(Al[q], Bh[gate][q], acc[gate], 0, 0, 0);
                    acc[gate] = __builtin_amdgcn_mfma_f32_16x16x32_bf16(Ah[q], Bl[gate][q], acc[gate], 0, 0, 0);
                }
            }
            #pragma unroll
            for (int r = 0; r < 4; r++) {
                const float ig = fsig(acc[0][r]);
                const float fg = fsig(acc[1][r]);
                const float gg = ftanh(acc[2][r]);
                const float og = fsig(acc[3][r]);
                const float c  = fg * cst[rt][r] + ig * gg;
                cst[rt][r] = c;
                const float h  = og * ftanh(c);
                if (t < WW - 1) {
                    const int node = 16 * rt + 4 * g + r;      // C row
                    const int col  = 16 + 16 * wv + l15;       // Z col of this dim
                    unsigned short hb = bf16h(h);
                    Zn[0][node][col] = (short)hb;
                    Zn[1][node][col] = (short)bf16h(h - bf16f(hb));
                } else {
                    const int node = n0 + 16 * rt + 4 * g + r;
                    if (node < nN) h_out[(size_t)node * HH + 16 * wv + l15] = h;
                }
            }
        }
        if (t < WW - 1)
            split_store4(&Zn[0][node_s][qq * 4], &Zn[1][node_s][qq * 4], xf);
        __syncthreads();
    }
}

// ---------------- degree / dis ----------------
__global__ void zero_kernel(float* __restrict__ p, int n) {
    int i = blockIdx.x * 256 + threadIdx.x;
    if (i < n) p[i] = 0.0f;
}

__global__ void deg_kernel(const int* __restrict__ dst, float* __restrict__ deg, int nE, int nN) {
    int e = blockIdx.x * 256 + threadIdx.x;
    if (e < nE) {
        int d = dst[e];
        if ((unsigned)d < (unsigned)nN) atomicAdd(&deg[d], 1.0f);
    }
}

__global__ void dis_kernel(float* __restrict__ deg_dis, int nN) {
    int i = blockIdx.x * 256 + threadIdx.x;
    if (i < nN) deg_dis[i] = rsqrtf(deg_dis[i] + 1.0f);
}

// ---------------- xw = act(in) @ W, fused with agg self-loop init ----------------
template<bool RELU_BIAS>
__global__ void xw_kernel(const float* __restrict__ A, const float* __restrict__ W,
                          const float* __restrict__ bias, const float* __restrict__ dis,
                          float* __restrict__ xw_out, float* __restrict__ agg_out, int nN)
{
    const int wave = threadIdx.x >> 6;
    const int lane = threadIdx.x & 63;
    const int n = blockIdx.x * 4 + wave;
    if (n >= nN) return;
    const float* arow = A + (size_t)n * HH;
    float acc = 0.0f;
    #pragma unroll
    for (int k = 0; k < HH; k++) {
        float a = arow[k];
        if (RELU_BIAS) a = fmaxf(a + bias[k], 0.0f);
        acc = fmaf(a, W[k * HH + lane], acc);
    }
    const float d = dis[n];
    xw_out[(size_t)n * HH + lane] = acc;
    agg_out[(size_t)n * HH + lane] = acc * d * d;   // self-loop term
}

// ---------------- edge scatter: one wave per edge ----------------
__global__ void scatter_kernel(const float* __restrict__ xw, const float* __restrict__ dis,
                               const int* __restrict__ src, const int* __restrict__ dst,
                               float* __restrict__ agg, int nE, int nN)
{
    const int e = blockIdx.x * 4 + (threadIdx.x >> 6);
    const int lane = threadIdx.x & 63;
    if (e >= nE) return;
    int s = src[e], d = dst[e];
    if ((unsigned)s >= (unsigned)nN || (unsigned)d >= (unsigned)nN) return;
    const float coef = dis[s] * dis[d];
    const float v = xw[(size_t)s * HH + lane] * coef;
    atomicAdd(&agg[(size_t)d * HH + lane], v);
}

// ---------------- head ----------------
__global__ void head_kernel(const float* __restrict__ agg, const float* __restrict__ b2,
                            const float* __restrict__ W_lin, const float* __restrict__ b_lin,
                            float* __restrict__ out, int nN)
{
    const int wave = threadIdx.x >> 6;
    const int lane = threadIdx.x & 63;
    const int n = blockIdx.x * 4 + wave;
    if (n >= nN) return;
    float v = fmaxf(agg[(size_t)n * HH + lane] + b2[lane], 0.0f) * W_lin[lane];
    #pragma unroll
    for (int off = 32; off > 0; off >>= 1) v += __shfl_down(v, off);
    if (lane == 0) out[n] = v + b_lin[0];
}

extern "C" void kernel_launch(void* const* d_in, const int* in_sizes, int n_in,
                              void* d_out, int out_size, void* d_ws, size_t ws_size,
                              hipStream_t stream)
{
    const float* x     = (const float*)d_in[0];
    const int*   edge  = (const int*)d_in[1];
    const float* W_ih  = (const float*)d_in[2];
    const float* W_hh  = (const float*)d_in[3];
    const float* b_ih  = (const float*)d_in[4];
    const float* b_hh  = (const float*)d_in[5];
    const float* W1    = (const float*)d_in[6];
    const float* b1    = (const float*)d_in[7];
    const float* W2    = (const float*)d_in[8];
    const float* b2    = (const float*)d_in[9];
    const float* W_lin = (const float*)d_in[10];
    const float* b_lin = (const float*)d_in[11];
    float* out = (float*)d_out;

    const int nN = in_sizes[0] / (WW * FF);   // 100000
    const int nE = in_sizes[1] / 2;           // 1600000
    const int* src = edge;
    const int* dst = edge + nE;

    float* ws = (float*)d_ws;
    const size_t npad = ((size_t)nN + 255) & ~(size_t)255;
    float* dis = ws;                       // [N]
    float* A   = ws + npad;                // [N,64]
    float* B   = A + (size_t)nN * HH;      // [N,64]
    float* C   = B + (size_t)nN * HH;      // [N,64]

    // degree -> dis
    zero_kernel<<<(nN + 255) / 256, 256, 0, stream>>>(dis, nN);
    deg_kernel<<<(nE + 255) / 256, 256, 0, stream>>>(dst, dis, nE, nN);
    dis_kernel<<<(nN + 255) / 256, 256, 0, stream>>>(dis, nN);

    // LSTM -> A = h_last
    lstm_mfma_kernel<<<(nN + 63) / 64, 256, 0, stream>>>(x, W_ih, W_hh, b_ih, b_hh, A, nN);

    // GCN layer 1: B = A @ W1 ; C = agg (self-loop init fused)
    xw_kernel<false><<<(nN + 3) / 4, 256, 0, stream>>>(A, W1, nullptr, dis, B, C, nN);
    scatter_kernel<<<(nE + 3) / 4, 256, 0, stream>>>(B, dis, src, dst, C, nE, nN);

    // GCN layer 2: A = relu(C + b1) @ W2 ; B = agg (self-loop init fused)
    xw_kernel<true><<<(nN + 3) / 4, 256, 0, stream>>>(C, W2, b1, dis, A, B, nN);
    scatter_kernel<<<(nE + 3) / 4, 256, 0, stream>>>(A, dis, src, dst, B, nE, nN);

    // head
    head_kernel<<<(nN + 3) / 4, 256, 0, stream>>>(B, b2, W_lin, b_lin, out, nN);
}

// Round 5
// 1573.937 us; speedup vs baseline: 6.1514x; 1.1407x over previous
//
#include <hip/hip_runtime.h>
#include <math.h>

#define WW 32
#define FF 16
#define HH 64

typedef __attribute__((ext_vector_type(8))) short bf16x8;
typedef __attribute__((ext_vector_type(4))) float f32x4;

__device__ __forceinline__ unsigned short bf16h(float f) {
    unsigned int u = __float_as_uint(f);
    unsigned int r = (u + 0x7FFFu + ((u >> 16) & 1u)) >> 16;
    return (unsigned short)r;
}
__device__ __forceinline__ float bf16f(unsigned short h) {
    return __uint_as_float(((unsigned int)h) << 16);
}
__device__ __forceinline__ float fsig(float v)  { return __fdividef(1.0f, 1.0f + __expf(-v)); }
__device__ __forceinline__ float ftanh(float v) { return 1.0f - __fdividef(2.0f, 1.0f + __expf(2.0f * v)); }

__device__ __forceinline__ void split_store4(short* dhi, short* dlo, float4 v) {
    short4 h, l;
    unsigned short t;
    t = bf16h(v.x); h.x = (short)t; l.x = (short)bf16h(v.x - bf16f(t));
    t = bf16h(v.y); h.y = (short)t; l.y = (short)bf16h(v.y - bf16f(t));
    t = bf16h(v.z); h.z = (short)t; l.z = (short)bf16h(v.z - bf16f(t));
    t = bf16h(v.w); h.w = (short)t; l.w = (short)bf16h(v.w - bf16f(t));
    *reinterpret_cast<short4*>(dhi) = h;
    *reinterpret_cast<short4*>(dlo) = l;
}

// ---------------- LSTM via MFMA (split-bf16 = fp32 accuracy) ----------------
__global__ __launch_bounds__(256, 2) void lstm_mfma_kernel(
    const float* __restrict__ x,      // [N,32,16]
    const float* __restrict__ W_ih,   // [256,16]
    const float* __restrict__ W_hh,   // [256,64]
    const float* __restrict__ b_ih,   // [256]
    const float* __restrict__ b_hh,   // [256]
    float* __restrict__ h_out,        // [N,64]
    int nN)
{
    __shared__ short Z[2][2][64][104];  // [buf][hi/lo][node][dim] 0-15 x, 16-79 h, pad
    const int tid  = threadIdx.x;
    const int lane = tid & 63;
    const int wv   = tid >> 6;
    const int l15  = lane & 15;
    const int g    = lane >> 4;
    const int n0   = blockIdx.x * 64;

    bf16x8 Bh[4][3], Bl[4][3];
    float bias[4];
    #pragma unroll
    for (int gate = 0; gate < 4; gate++) {
        const int j = 16 * wv + 64 * gate + l15;
        bias[gate] = b_ih[j] + b_hh[j];
        #pragma unroll
        for (int q = 0; q < 3; q++) {
            const int k0 = 32 * q + 8 * g;
            float v[8];
            if (k0 < 16) {
                const float4* p = reinterpret_cast<const float4*>(W_ih + j * FF + k0);
                float4 a = p[0], b = p[1];
                v[0]=a.x; v[1]=a.y; v[2]=a.z; v[3]=a.w; v[4]=b.x; v[5]=b.y; v[6]=b.z; v[7]=b.w;
            } else if (k0 < 80) {
                const float4* p = reinterpret_cast<const float4*>(W_hh + j * HH + (k0 - 16));
                float4 a = p[0], b = p[1];
                v[0]=a.x; v[1]=a.y; v[2]=a.z; v[3]=a.w; v[4]=b.x; v[5]=b.y; v[6]=b.z; v[7]=b.w;
            } else {
                #pragma unroll
                for (int i = 0; i < 8; i++) v[i] = 0.0f;
            }
            bf16x8 hi, lo;
            #pragma unroll
            for (int i = 0; i < 8; i++) {
                unsigned short hb = bf16h(v[i]);
                hi[i] = (short)hb;
                lo[i] = (short)bf16h(v[i] - bf16f(hb));
            }
            Bh[gate][q] = hi; Bl[gate][q] = lo;
        }
    }

    const int node_s = tid >> 2;
    const int qq     = tid & 3;
    {
        #pragma unroll
        for (int b = 0; b < 2; b++)
            #pragma unroll
            for (int s = 0; s < 2; s++)
                #pragma unroll
                for (int c = 0; c < 6; c++)
                    Z[b][s][node_s][80 + qq * 6 + c] = 0;
        #pragma unroll
        for (int s = 0; s < 2; s++)
            #pragma unroll
            for (int c = 0; c < 16; c++)
                Z[0][s][node_s][16 + qq * 16 + c] = 0;
        int gn = n0 + node_s; if (gn >= nN) gn = nN - 1;
        const float4 xf = *reinterpret_cast<const float4*>(x + (size_t)gn * (WW * FF) + qq * 4);
        split_store4(&Z[0][0][node_s][qq * 4], &Z[0][1][node_s][qq * 4], xf);
    }
    __syncthreads();

    f32x4 cst[4] = {{0.f,0.f,0.f,0.f},{0.f,0.f,0.f,0.f},{0.f,0.f,0.f,0.f},{0.f,0.f,0.f,0.f}};

    for (int t = 0; t < WW; t++) {
        short (*Zc)[64][104] = Z[t & 1];
        short (*Zn)[64][104] = Z[(t & 1) ^ 1];

        int gn = n0 + node_s; if (gn >= nN) gn = nN - 1;
        const int tn = (t + 1 < WW) ? (t + 1) : (WW - 1);
        const float4 xf = *reinterpret_cast<const float4*>(x + (size_t)gn * (WW * FF) + tn * FF + qq * 4);

        #pragma unroll
        for (int rt = 0; rt < 4; rt++) {
            const int m = 16 * rt + l15;
            bf16x8 Ah[3], Al[3];
            #pragma unroll
            for (int q = 0; q < 3; q++) {
                const int k0 = 32 * q + 8 * g;
                Ah[q] = *reinterpret_cast<const bf16x8*>(&Zc[0][m][k0]);
                Al[q] = *reinterpret_cast<const bf16x8*>(&Zc[1][m][k0]);
            }
            f32x4 acc[4];
            #pragma unroll
            for (int gate = 0; gate < 4; gate++) {
                f32x4 ini = {bias[gate], bias[gate], bias[gate], bias[gate]};
                acc[gate] = ini;
            }
            #pragma unroll
            for (int q = 0; q < 3; q++) {
                #pragma unroll
                for (int gate = 0; gate < 4; gate++) {
                    acc[gate] = __builtin_amdgcn_mfma_f32_16x16x32_bf16(Ah[q], Bh[gate][q], acc[gate], 0, 0, 0);
                    acc[gate] = __builtin_amdgcn_mfma_f32_16x16x32_bf16(Al[q], Bh[gate][q], acc[gate], 0, 0, 0);
                    acc[gate] = __builtin_amdgcn_mfma_f32_16x16x32_bf16(Ah[q], Bl[gate][q], acc[gate], 0, 0, 0);
                }
            }
            #pragma unroll
            for (int r = 0; r < 4; r++) {
                const float ig = fsig(acc[0][r]);
                const float fg = fsig(acc[1][r]);
                const float gg = ftanh(acc[2][r]);
                const float og = fsig(acc[3][r]);
                const float c  = fg * cst[rt][r] + ig * gg;
                cst[rt][r] = c;
                const float h  = og * ftanh(c);
                if (t < WW - 1) {
                    const int node = 16 * rt + 4 * g + r;
                    const int col  = 16 + 16 * wv + l15;
                    unsigned short hb = bf16h(h);
                    Zn[0][node][col] = (short)hb;
                    Zn[1][node][col] = (short)bf16h(h - bf16f(hb));
                } else {
                    const int node = n0 + 16 * rt + 4 * g + r;
                    if (node < nN) h_out[(size_t)node * HH + 16 * wv + l15] = h;
                }
            }
        }
        if (t < WW - 1)
            split_store4(&Zn[0][node_s][qq * 4], &Zn[1][node_s][qq * 4], xf);
        __syncthreads();
    }
}

// ---------------- CSR build ----------------
__global__ void zero_int_kernel(int* __restrict__ p, int n) {
    int i = blockIdx.x * 256 + threadIdx.x;
    if (i < n) p[i] = 0;
}

__global__ void deg_int_kernel(const int* __restrict__ dst, int* __restrict__ deg, int nE, int nN) {
    int e = blockIdx.x * 256 + threadIdx.x;
    if (e < nE) {
        int d = dst[e];
        if ((unsigned)d < (unsigned)nN) atomicAdd(&deg[d], 1);
    }
}

__global__ void dis_from_deg_kernel(const int* __restrict__ deg, float* __restrict__ dis, int nN) {
    int i = blockIdx.x * 256 + threadIdx.x;
    if (i < nN) dis[i] = rsqrtf((float)deg[i] + 1.0f);
}

// single-block scan: row_ptr[n] = exclusive prefix of deg; cursor[n] = row_ptr[n]
__global__ __launch_bounds__(1024) void scan_kernel(const int* __restrict__ deg,
                                                    int* __restrict__ row_ptr,
                                                    int* __restrict__ cursor, int nN)
{
    __shared__ int part[1024];
    const int tid = threadIdx.x;
    const int chunk = (nN + 1023) / 1024;
    const int s = tid * chunk;
    const int e = min(s + chunk, nN);
    int sum = 0;
    for (int i = s; i < e; i++) sum += deg[i];
    part[tid] = sum;
    __syncthreads();
    if (tid == 0) {
        int acc = 0;
        for (int i = 0; i < 1024; i++) { int v = part[i]; part[i] = acc; acc += v; }
    }
    __syncthreads();
    int acc = part[tid];
    for (int i = s; i < e; i++) {
        row_ptr[i] = acc;
        cursor[i]  = acc;
        acc += deg[i];
    }
}

__global__ void place_kernel(const int* __restrict__ src, const int* __restrict__ dst,
                             const float* __restrict__ dis, int* __restrict__ cursor,
                             int* __restrict__ csr_src, float* __restrict__ csr_dis,
                             int nE, int nN)
{
    int e = blockIdx.x * 256 + threadIdx.x;
    if (e >= nE) return;
    int s = src[e], d = dst[e];
    if ((unsigned)s >= (unsigned)nN || (unsigned)d >= (unsigned)nN) return;
    int pos = atomicAdd(&cursor[d], 1);
    csr_src[pos] = s;
    csr_dis[pos] = dis[s];
}

// ---------------- xw = act(in) @ W ----------------
template<bool RELU_BIAS, bool WRITE_AGG>
__global__ void xw_kernel(const float* __restrict__ A, const float* __restrict__ W,
                          const float* __restrict__ bias, const float* __restrict__ dis,
                          float* __restrict__ xw_out, float* __restrict__ agg_out, int nN)
{
    const int wave = threadIdx.x >> 6;
    const int lane = threadIdx.x & 63;
    const int n = blockIdx.x * 4 + wave;
    if (n >= nN) return;
    const float* arow = A + (size_t)n * HH;
    float acc = 0.0f;
    #pragma unroll
    for (int k = 0; k < HH; k++) {
        float a = arow[k];
        if (RELU_BIAS) a = fmaxf(a + bias[k], 0.0f);
        acc = fmaf(a, W[k * HH + lane], acc);
    }
    xw_out[(size_t)n * HH + lane] = acc;
    if (WRITE_AGG) {
        const float d = dis[n];
        agg_out[(size_t)n * HH + lane] = acc * d * d;
    }
}

// ---------------- gather: wave per node, no atomics ----------------
// agg[n] = dis[n] * ( dis[n]*xw[n] + sum_e dis[src_e]*xw[src_e] )
// FINAL: fuse regression head instead of storing agg.
template<bool FINAL>
__global__ void gather_kernel(const float* __restrict__ xw, const float* __restrict__ dis,
                              const int* __restrict__ row_ptr, const int* __restrict__ deg,
                              const int* __restrict__ csr_src, const float* __restrict__ csr_dis,
                              float* __restrict__ agg_out,
                              const float* __restrict__ b2, const float* __restrict__ W_lin,
                              const float* __restrict__ b_lin, float* __restrict__ out, int nN)
{
    const int wave = threadIdx.x >> 6;
    const int lane = threadIdx.x & 63;
    const int n = blockIdx.x * 4 + wave;
    if (n >= nN) return;
    const float dn = dis[n];
    float v = xw[(size_t)n * HH + lane] * dn;   // self-loop
    const int start = row_ptr[n];
    const int cnt   = deg[n];
    int i = start;
    const int end = start + cnt;
    for (; i + 1 < end; i += 2) {
        int s0 = csr_src[i];     float c0 = csr_dis[i];
        int s1 = csr_src[i + 1]; float c1 = csr_dis[i + 1];
        v = fmaf(xw[(size_t)s0 * HH + lane], c0, v);
        v = fmaf(xw[(size_t)s1 * HH + lane], c1, v);
    }
    if (i < end) {
        int s0 = csr_src[i]; float c0 = csr_dis[i];
        v = fmaf(xw[(size_t)s0 * HH + lane], c0, v);
    }
    v *= dn;
    if (FINAL) {
        float val = fmaxf(v + b2[lane], 0.0f) * W_lin[lane];
        #pragma unroll
        for (int off = 32; off > 0; off >>= 1) val += __shfl_down(val, off);
        if (lane == 0) out[n] = val + b_lin[0];
    } else {
        agg_out[(size_t)n * HH + lane] = v;
    }
}

// ---------------- fallback: atomic scatter path ----------------
__global__ void scatter_kernel(const float* __restrict__ xw, const float* __restrict__ dis,
                               const int* __restrict__ src, const int* __restrict__ dst,
                               float* __restrict__ agg, int nE, int nN)
{
    const int e = blockIdx.x * 4 + (threadIdx.x >> 6);
    const int lane = threadIdx.x & 63;
    if (e >= nE) return;
    int s = src[e], d = dst[e];
    if ((unsigned)s >= (unsigned)nN || (unsigned)d >= (unsigned)nN) return;
    const float coef = dis[s] * dis[d];
    const float v = xw[(size_t)s * HH + lane] * coef;
    atomicAdd(&agg[(size_t)d * HH + lane], v);
}

__global__ void head_kernel(const float* __restrict__ agg, const float* __restrict__ b2,
                            const float* __restrict__ W_lin, const float* __restrict__ b_lin,
                            float* __restrict__ out, int nN)
{
    const int wave = threadIdx.x >> 6;
    const int lane = threadIdx.x & 63;
    const int n = blockIdx.x * 4 + wave;
    if (n >= nN) return;
    float v = fmaxf(agg[(size_t)n * HH + lane] + b2[lane], 0.0f) * W_lin[lane];
    #pragma unroll
    for (int off = 32; off > 0; off >>= 1) v += __shfl_down(v, off);
    if (lane == 0) out[n] = v + b_lin[0];
}

extern "C" void kernel_launch(void* const* d_in, const int* in_sizes, int n_in,
                              void* d_out, int out_size, void* d_ws, size_t ws_size,
                              hipStream_t stream)
{
    const float* x     = (const float*)d_in[0];
    const int*   edge  = (const int*)d_in[1];
    const float* W_ih  = (const float*)d_in[2];
    const float* W_hh  = (const float*)d_in[3];
    const float* b_ih  = (const float*)d_in[4];
    const float* b_hh  = (const float*)d_in[5];
    const float* W1    = (const float*)d_in[6];
    const float* b1    = (const float*)d_in[7];
    const float* W2    = (const float*)d_in[8];
    const float* b2    = (const float*)d_in[9];
    const float* W_lin = (const float*)d_in[10];
    const float* b_lin = (const float*)d_in[11];
    float* out = (float*)d_out;

    const int nN = in_sizes[0] / (WW * FF);   // 100000
    const int nE = in_sizes[1] / 2;           // 1600000
    const int* src = edge;
    const int* dst = edge + nE;

    float* ws = (float*)d_ws;
    const size_t npad = ((size_t)nN + 255) & ~(size_t)255;
    float* dis = ws;                           // [N]
    float* A   = ws + npad;                    // [N,64]
    float* B   = A + (size_t)nN * HH;          // [N,64]
    float* C   = B + (size_t)nN * HH;          // [N,64]
    // CSR region (after C)
    int*   deg_i   = (int*)(C + (size_t)nN * HH);   // [N]
    int*   row_ptr = deg_i + npad;                  // [N]
    int*   cursor  = row_ptr + npad;                // [N]
    int*   csr_src = cursor + npad;                 // [E]
    float* csr_dis = (float*)(csr_src + nE);        // [E]

    const size_t need = (npad + 3 * (size_t)nN * HH + 3 * npad + 2 * (size_t)nE) * 4;
    const bool use_csr = (ws_size >= need);

    const int gN256 = (nN + 255) / 256;
    const int gE256 = (nE + 255) / 256;
    const int gN4   = (nN + 3) / 4;

    if (use_csr) {
        // CSR build
        zero_int_kernel<<<gN256, 256, 0, stream>>>(deg_i, nN);
        deg_int_kernel<<<gE256, 256, 0, stream>>>(dst, deg_i, nE, nN);
        dis_from_deg_kernel<<<gN256, 256, 0, stream>>>(deg_i, dis, nN);
        scan_kernel<<<1, 1024, 0, stream>>>(deg_i, row_ptr, cursor, nN);
        place_kernel<<<gE256, 256, 0, stream>>>(src, dst, dis, cursor, csr_src, csr_dis, nE, nN);

        // LSTM -> A
        lstm_mfma_kernel<<<(nN + 63) / 64, 256, 0, stream>>>(x, W_ih, W_hh, b_ih, b_hh, A, nN);

        // layer 1: B = A@W1 ; C = gather(B)
        xw_kernel<false, false><<<gN4, 256, 0, stream>>>(A, W1, nullptr, dis, B, nullptr, nN);
        gather_kernel<false><<<gN4, 256, 0, stream>>>(B, dis, row_ptr, deg_i, csr_src, csr_dis,
                                                      C, nullptr, nullptr, nullptr, nullptr, nN);
        // layer 2: B = relu(C+b1)@W2 ; gather + head -> out
        xw_kernel<true, false><<<gN4, 256, 0, stream>>>(C, W2, b1, dis, B, nullptr, nN);
        gather_kernel<true><<<gN4, 256, 0, stream>>>(B, dis, row_ptr, deg_i, csr_src, csr_dis,
                                                     nullptr, b2, W_lin, b_lin, out, nN);
    } else {
        // fallback: original atomic-scatter pipeline
        zero_int_kernel<<<gN256, 256, 0, stream>>>(deg_i, nN);
        deg_int_kernel<<<gE256, 256, 0, stream>>>(dst, deg_i, nE, nN);
        dis_from_deg_kernel<<<gN256, 256, 0, stream>>>(deg_i, dis, nN);

        lstm_mfma_kernel<<<(nN + 63) / 64, 256, 0, stream>>>(x, W_ih, W_hh, b_ih, b_hh, A, nN);

        xw_kernel<false, true><<<gN4, 256, 0, stream>>>(A, W1, nullptr, dis, B, C, nN);
        scatter_kernel<<<(nE + 3) / 4, 256, 0, stream>>>(B, dis, src, dst, C, nE, nN);

        xw_kernel<true, true><<<gN4, 256, 0, stream>>>(C, W2, b1, dis, A, B, nN);
        scatter_kernel<<<(nE + 3) / 4, 256, 0, stream>>>(A, dis, src, dst, B, nE, nN);

        head_kernel<<<gN4, 256, 0, stream>>>(B, b2, W_lin, b_lin, out, nN);
    }
}